// Round 2
// baseline (5328.560 us; speedup 1.0000x reference)
//
#include <hip/hip_runtime.h>

#define B_SZ    2
#define LSEQ    2048
#define DMODEL  768
#define DINNER  1536
#define NHEADS  24
#define HD      64
#define CDPH    192
#define CONVDIM 4608
#define DIP     6168
#define MROWS   (B_SZ*LSEQ)   // 4096

__device__ __forceinline__ float siluf(float x) {
    return x / (1.0f + __expf(-x));
}

// C[m,n] = sum_k A[m,k] * B[n,k];  A:[M,K] row-major, B:[N,K] row-major.
__global__ __launch_bounds__(256) void gemm_nt_f32(
    const float* __restrict__ A, const float* __restrict__ B,
    float* __restrict__ C, int M, int N, int K)
{
    __shared__ __attribute__((aligned(16))) float As[16][132];
    __shared__ __attribute__((aligned(16))) float Bs[16][68];
    const int ntn = (N + 63) >> 6;
    const int bm = blockIdx.x / ntn;
    const int bn = blockIdx.x - bm * ntn;
    const int m0 = bm << 7, n0 = bn << 6;
    const int tid = threadIdx.x;
    const int tx = tid & 15, ty = tid >> 4;

    float acc[8][4];
#pragma unroll
    for (int i = 0; i < 8; ++i)
#pragma unroll
        for (int j = 0; j < 4; ++j) acc[i][j] = 0.f;

    const int ar = tid >> 1;
    const int ac = (tid & 1) << 3;
    const int br = tid >> 2;
    const int bc = (tid & 3) << 2;
    const float* Ap = A + (size_t)(m0 + ar) * K + ac;
    const bool bval = (n0 + br) < N;
    const float* Bp = B + (size_t)(n0 + br) * K + bc;

    for (int k0 = 0; k0 < K; k0 += 16) {
        const float4 a0 = *(const float4*)(Ap + k0);
        const float4 a1 = *(const float4*)(Ap + k0 + 4);
        float4 bv = make_float4(0.f, 0.f, 0.f, 0.f);
        if (bval) bv = *(const float4*)(Bp + k0);
        __syncthreads();
        As[ac + 0][ar] = a0.x; As[ac + 1][ar] = a0.y;
        As[ac + 2][ar] = a0.z; As[ac + 3][ar] = a0.w;
        As[ac + 4][ar] = a1.x; As[ac + 5][ar] = a1.y;
        As[ac + 6][ar] = a1.z; As[ac + 7][ar] = a1.w;
        Bs[bc + 0][br] = bv.x; Bs[bc + 1][br] = bv.y;
        Bs[bc + 2][br] = bv.z; Bs[bc + 3][br] = bv.w;
        __syncthreads();
#pragma unroll
        for (int k = 0; k < 16; ++k) {
            const float4 av0 = *(const float4*)&As[k][ty << 3];
            const float4 av1 = *(const float4*)&As[k][(ty << 3) + 4];
            const float4 bvv = *(const float4*)&Bs[k][tx << 2];
            const float aa[8] = {av0.x, av0.y, av0.z, av0.w,
                                 av1.x, av1.y, av1.z, av1.w};
            const float bb[4] = {bvv.x, bvv.y, bvv.z, bvv.w};
#pragma unroll
            for (int i = 0; i < 8; ++i)
#pragma unroll
                for (int j = 0; j < 4; ++j)
                    acc[i][j] = fmaf(aa[i], bb[j], acc[i][j]);
        }
    }
#pragma unroll
    for (int i = 0; i < 8; ++i) {
        const int m = m0 + (ty << 3) + i;
        float* Cr = C + (size_t)m * N + n0 + (tx << 2);
#pragma unroll
        for (int j = 0; j < 4; ++j)
            if (n0 + (tx << 2) + j < N) Cr[j] = acc[i][j];
    }
}

// Single-wave scan: one 64-lane wave per (b,h). Zero barriers -> prefetch of
// t+1 global data survives the whole step; all cross-lane traffic is
// wave-internal LDS (lgkmcnt only).
// Lane l owns: rows l of R_x/R_B/R_C (registers), state row l (64 regs),
// conv channels {l, 64+l, 128+l} (register history).
__global__ __launch_bounds__(64, 1) void mamba_scan1(
    const float* __restrict__ zx,      // [4096, DIP]
    const float* __restrict__ conv_w,  // [4608, 4]
    const float* __restrict__ conv_b,  // [4608]
    const float* __restrict__ R_x,     // [24,64,64]
    const float* __restrict__ R_B,
    const float* __restrict__ R_C,
    const float* __restrict__ R_dt,    // [24,64]
    const float* __restrict__ dt_bias, // [24]
    const float* __restrict__ A_log,   // [24]
    const float* __restrict__ Dvec,    // [24,64]
    float* __restrict__ yz)            // [4096, 1536]
{
    const int b = blockIdx.x / NHEADS;
    const int h = blockIdx.x % NHEADS;
    const int l = threadIdx.x;  // 0..63

    __shared__ __attribute__((aligned(16))) float ybuf[64];
    __shared__ __attribute__((aligned(16))) float bcbuf[128];  // B | C
    __shared__ __attribute__((aligned(16))) float rdtl[64];

    // ---- R rows into registers ----
    float Rxr[64], Rbr[64], Rcr[64];
    {
        const size_t rowoff = ((size_t)h * 64 + l) * 64;
#pragma unroll
        for (int j = 0; j < 64; j += 4) {
            const float4 v = *(const float4*)(R_x + rowoff + j);
            Rxr[j] = v.x; Rxr[j+1] = v.y; Rxr[j+2] = v.z; Rxr[j+3] = v.w;
        }
#pragma unroll
        for (int j = 0; j < 64; j += 4) {
            const float4 v = *(const float4*)(R_B + rowoff + j);
            Rbr[j] = v.x; Rbr[j+1] = v.y; Rbr[j+2] = v.z; Rbr[j+3] = v.w;
        }
#pragma unroll
        for (int j = 0; j < 64; j += 4) {
            const float4 v = *(const float4*)(R_C + rowoff + j);
            Rcr[j] = v.x; Rcr[j+1] = v.y; Rcr[j+2] = v.z; Rcr[j+3] = v.w;
        }
    }
    rdtl[l] = R_dt[h * 64 + l];
    ybuf[l] = 0.f;

    const float Aval = -__expf(A_log[h]);
    const float bias = dt_bias[h];
    const float dval = Dvec[h * 64 + l];

    // ---- conv params: 3 channels per lane ----
    float wx0, wx1, wx2, wx3, wb0, wb1, wb2, wb3, wc0, wc1, wc2, wc3;
    float cbx, cbB, cbC;
    {
        const float* cw = conv_w + (size_t)h * CDPH * 4;
        const float4 vx = *(const float4*)(cw + (size_t)l * 4);
        const float4 vb = *(const float4*)(cw + (size_t)(64 + l) * 4);
        const float4 vc = *(const float4*)(cw + (size_t)(128 + l) * 4);
        wx0 = vx.x; wx1 = vx.y; wx2 = vx.z; wx3 = vx.w;
        wb0 = vb.x; wb1 = vb.y; wb2 = vb.z; wb3 = vb.w;
        wc0 = vc.x; wc1 = vc.y; wc2 = vc.z; wc3 = vc.w;
        cbx = conv_b[h * CDPH + l];
        cbB = conv_b[h * CDPH + 64 + l];
        cbC = conv_b[h * CDPH + 128 + l];
    }
    float hx0 = 0.f, hx1 = 0.f, hx2 = 0.f;
    float hB0 = 0.f, hB1 = 0.f, hB2 = 0.f;
    float hC0 = 0.f, hC1 = 0.f, hC2 = 0.f;

    const float* xbc = zx + (size_t)b * LSEQ * DIP + DINNER + h * CDPH;
    const float* zb  = zx + (size_t)b * LSEQ * DIP + h * HD;
    const float* dtr = zx + (size_t)b * LSEQ * DIP + DINNER + CONVDIM + h;
    float* yzb = yz + (size_t)b * LSEQ * DINNER + h * HD;

    float st[64];
#pragma unroll
    for (int j = 0; j < 64; ++j) st[j] = 0.f;

    // preload t=0 inputs (all lanes same addr for dtr -> broadcast)
    float vx_c = xbc[l], vB_c = xbc[64 + l], vC_c = xbc[128 + l];
    float z_c = zb[l];
    float dtr_c = dtr[0];

    __builtin_amdgcn_s_waitcnt(0);  // lgkm: rdtl/ybuf visible (single wave)

    for (int t = 0; t < LSEQ; ++t) {
        // ---- conv (independent of y; fills y-LDS latency) ----
        const float xcx = fmaf(wx3, vx_c, fmaf(wx2, hx2, fmaf(wx1, hx1, fmaf(wx0, hx0, cbx))));
        const float xcB = fmaf(wb3, vB_c, fmaf(wb2, hB2, fmaf(wb1, hB1, fmaf(wb0, hB0, cbB))));
        const float xcC = fmaf(wc3, vC_c, fmaf(wc2, hC2, fmaf(wc1, hC1, fmaf(wc0, hC0, cbC))));
        hx0 = hx1; hx1 = hx2; hx2 = vx_c;
        hB0 = hB1; hB1 = hB2; hB2 = vB_c;
        hC0 = hC1; hC1 = hC2; hC2 = vC_c;

        // ---- prefetch t+1 (hidden under the whole step; no barriers) ----
        const size_t roff = (size_t)((t + 1 < LSEQ) ? t + 1 : t) * DIP;
        const float vx_n = xbc[roff + l];
        const float vB_n = xbc[roff + 64 + l];
        const float vC_n = xbc[roff + 128 + l];
        const float z_n  = zb[roff + l];
        const float dtr_n = dtr[roff];

        // ---- phase A1: B,C dots (needed first -> written to LDS early) ----
        float ab = 0.f, ac = 0.f;
#pragma unroll
        for (int c = 0; c < 4; ++c) {
            const float4 y0 = *(const float4*)&ybuf[c * 16 + 0];
            const float4 y1 = *(const float4*)&ybuf[c * 16 + 4];
            const float4 y2 = *(const float4*)&ybuf[c * 16 + 8];
            const float4 y3 = *(const float4*)&ybuf[c * 16 + 12];
            const float yv[16] = {y0.x, y0.y, y0.z, y0.w, y1.x, y1.y, y1.z, y1.w,
                                  y2.x, y2.y, y2.z, y2.w, y3.x, y3.y, y3.z, y3.w};
#pragma unroll
            for (int j = 0; j < 16; ++j) {
                ab = fmaf(Rbr[c * 16 + j], yv[j], ab);
                ac = fmaf(Rcr[c * 16 + j], yv[j], ac);
            }
        }
        const float Bm = siluf(xcB + ab);
        const float Cm = siluf(xcC + ac);
        bcbuf[l] = Bm;
        bcbuf[64 + l] = Cm;

        // ---- phase A2: x,dt dots (hide the B/C LDS write->read latency) ----
        float ax = 0.f, ad = 0.f;
#pragma unroll
        for (int c = 0; c < 4; ++c) {
            const float4 y0 = *(const float4*)&ybuf[c * 16 + 0];
            const float4 y1 = *(const float4*)&ybuf[c * 16 + 4];
            const float4 y2 = *(const float4*)&ybuf[c * 16 + 8];
            const float4 y3 = *(const float4*)&ybuf[c * 16 + 12];
            const float4 r0 = *(const float4*)&rdtl[c * 16 + 0];
            const float4 r1 = *(const float4*)&rdtl[c * 16 + 4];
            const float4 r2 = *(const float4*)&rdtl[c * 16 + 8];
            const float4 r3 = *(const float4*)&rdtl[c * 16 + 12];
            const float yv[16] = {y0.x, y0.y, y0.z, y0.w, y1.x, y1.y, y1.z, y1.w,
                                  y2.x, y2.y, y2.z, y2.w, y3.x, y3.y, y3.z, y3.w};
            const float rv[16] = {r0.x, r0.y, r0.z, r0.w, r1.x, r1.y, r1.z, r1.w,
                                  r2.x, r2.y, r2.z, r2.w, r3.x, r3.y, r3.z, r3.w};
#pragma unroll
            for (int j = 0; j < 16; ++j) {
                ax = fmaf(Rxr[c * 16 + j], yv[j], ax);
                ad = fmaf(rv[j], yv[j], ad);
            }
        }
        const float xv = siluf(xcx + ax);
        const float dv = dtr_c + ad + bias;
        const float dtv = (dv > 20.f) ? dv : log1pf(__expf(dv));
        const float dAv = __expf(dtv * Aval);
        const float kx = dtv * xv;

        // ---- phase B: state update + output dot (row l) ----
        float ya0 = 0.f, ya1 = 0.f, ya2 = 0.f, ya3 = 0.f;
#pragma unroll
        for (int c = 0; c < 4; ++c) {
            const float4 b0 = *(const float4*)&bcbuf[c * 16 + 0];
            const float4 b1 = *(const float4*)&bcbuf[c * 16 + 4];
            const float4 b2 = *(const float4*)&bcbuf[c * 16 + 8];
            const float4 b3 = *(const float4*)&bcbuf[c * 16 + 12];
            const float4 c0 = *(const float4*)&bcbuf[64 + c * 16 + 0];
            const float4 c1 = *(const float4*)&bcbuf[64 + c * 16 + 4];
            const float4 c2 = *(const float4*)&bcbuf[64 + c * 16 + 8];
            const float4 c3 = *(const float4*)&bcbuf[64 + c * 16 + 12];
            const float bv[16] = {b0.x, b0.y, b0.z, b0.w, b1.x, b1.y, b1.z, b1.w,
                                  b2.x, b2.y, b2.z, b2.w, b3.x, b3.y, b3.z, b3.w};
            const float cv[16] = {c0.x, c0.y, c0.z, c0.w, c1.x, c1.y, c1.z, c1.w,
                                  c2.x, c2.y, c2.z, c2.w, c3.x, c3.y, c3.z, c3.w};
            float yl = 0.f;
#pragma unroll
            for (int j = 0; j < 16; ++j) {
                const int s = c * 16 + j;
                st[s] = fmaf(st[s], dAv, kx * bv[j]);
                yl = fmaf(st[s], cv[j], yl);
            }
            if (c == 0) ya0 = yl; else if (c == 1) ya1 = yl;
            else if (c == 2) ya2 = yl; else ya3 = yl;
        }
        const float yv_new = (ya0 + ya1) + (ya2 + ya3) + dval * xv;

        // broadcast y for next step; store gated output
        ybuf[l] = yv_new;
        yzb[(size_t)t * DINNER + l] = yv_new * siluf(z_c);

        vx_c = vx_n; vB_c = vB_n; vC_c = vC_n; z_c = z_n; dtr_c = dtr_n;
    }
}

extern "C" void kernel_launch(void* const* d_in, const int* in_sizes, int n_in,
                              void* d_out, int out_size, void* d_ws, size_t ws_size,
                              hipStream_t stream) {
    const float* u       = (const float*)d_in[0];
    const float* W_in    = (const float*)d_in[1];
    const float* conv_w  = (const float*)d_in[2];
    const float* conv_b  = (const float*)d_in[3];
    const float* R_x     = (const float*)d_in[4];
    const float* R_B     = (const float*)d_in[5];
    const float* R_C     = (const float*)d_in[6];
    const float* R_dt    = (const float*)d_in[7];
    const float* dt_bias = (const float*)d_in[8];
    const float* A_log   = (const float*)d_in[9];
    const float* Dv      = (const float*)d_in[10];
    const float* W_out   = (const float*)d_in[11];
    float* out = (float*)d_out;

    float* zx = (float*)d_ws;                      // [4096, 6168]
    float* yz = zx + (size_t)MROWS * DIP;          // [4096, 1536]

    {   // in-projection
        const int M = MROWS, N = DIP, K = DMODEL;
        const int grid = (M / 128) * ((N + 63) / 64);
        gemm_nt_f32<<<grid, 256, 0, stream>>>(u, W_in, zx, M, N, K);
    }
    mamba_scan1<<<B_SZ * NHEADS, 64, 0, stream>>>(
        zx, conv_w, conv_b, R_x, R_B, R_C, R_dt, dt_bias, A_log, Dv, yz);
    {   // out-projection
        const int M = MROWS, N = DMODEL, K = DINNER;
        const int grid = (M / 128) * ((N + 63) / 64);
        gemm_nt_f32<<<grid, 256, 0, stream>>>(yz, W_out, out, M, N, K);
    }
}

// Round 3
// 3593.215 us; speedup vs baseline: 1.4830x; 1.4830x over previous
//
#include <hip/hip_runtime.h>

#define B_SZ    2
#define LSEQ    2048
#define DMODEL  768
#define DINNER  1536
#define NHEADS  24
#define HD      64
#define CDPH    192
#define CONVDIM 4608
#define DIP     6168
#define MROWS   (B_SZ*LSEQ)   // 4096

__device__ __forceinline__ float siluf(float x) {
    return x / (1.0f + __expf(-x));
}

// lgkm-only barrier: does NOT drain vmcnt, so global prefetches stay in
// flight across it. "memory" clobbers pin LDS ops on each side.
#define WBAR() do { asm volatile("s_waitcnt lgkmcnt(0)" ::: "memory"); \
                    __builtin_amdgcn_s_barrier();                      \
                    asm volatile("" ::: "memory"); } while (0)

// C[m,n] = sum_k A[m,k] * B[n,k];  A:[M,K] row-major, B:[N,K] row-major.
__global__ __launch_bounds__(256) void gemm_nt_f32(
    const float* __restrict__ A, const float* __restrict__ B,
    float* __restrict__ C, int M, int N, int K)
{
    __shared__ __attribute__((aligned(16))) float As[16][132];
    __shared__ __attribute__((aligned(16))) float Bs[16][68];
    const int ntn = (N + 63) >> 6;
    const int bm = blockIdx.x / ntn;
    const int bn = blockIdx.x - bm * ntn;
    const int m0 = bm << 7, n0 = bn << 6;
    const int tid = threadIdx.x;
    const int tx = tid & 15, ty = tid >> 4;

    float acc[8][4];
#pragma unroll
    for (int i = 0; i < 8; ++i)
#pragma unroll
        for (int j = 0; j < 4; ++j) acc[i][j] = 0.f;

    const int ar = tid >> 1;
    const int ac = (tid & 1) << 3;
    const int br = tid >> 2;
    const int bc = (tid & 3) << 2;
    const float* Ap = A + (size_t)(m0 + ar) * K + ac;
    const bool bval = (n0 + br) < N;
    const float* Bp = B + (size_t)(n0 + br) * K + bc;

    for (int k0 = 0; k0 < K; k0 += 16) {
        const float4 a0 = *(const float4*)(Ap + k0);
        const float4 a1 = *(const float4*)(Ap + k0 + 4);
        float4 bv = make_float4(0.f, 0.f, 0.f, 0.f);
        if (bval) bv = *(const float4*)(Bp + k0);
        __syncthreads();
        As[ac + 0][ar] = a0.x; As[ac + 1][ar] = a0.y;
        As[ac + 2][ar] = a0.z; As[ac + 3][ar] = a0.w;
        As[ac + 4][ar] = a1.x; As[ac + 5][ar] = a1.y;
        As[ac + 6][ar] = a1.z; As[ac + 7][ar] = a1.w;
        Bs[bc + 0][br] = bv.x; Bs[bc + 1][br] = bv.y;
        Bs[bc + 2][br] = bv.z; Bs[bc + 3][br] = bv.w;
        __syncthreads();
#pragma unroll
        for (int k = 0; k < 16; ++k) {
            const float4 av0 = *(const float4*)&As[k][ty << 3];
            const float4 av1 = *(const float4*)&As[k][(ty << 3) + 4];
            const float4 bvv = *(const float4*)&Bs[k][tx << 2];
            const float aa[8] = {av0.x, av0.y, av0.z, av0.w,
                                 av1.x, av1.y, av1.z, av1.w};
            const float bb[4] = {bvv.x, bvv.y, bvv.z, bvv.w};
#pragma unroll
            for (int i = 0; i < 8; ++i)
#pragma unroll
                for (int j = 0; j < 4; ++j)
                    acc[i][j] = fmaf(aa[i], bb[j], acc[i][j]);
        }
    }
#pragma unroll
    for (int i = 0; i < 8; ++i) {
        const int m = m0 + (ty << 3) + i;
        float* Cr = C + (size_t)m * N + n0 + (tx << 2);
#pragma unroll
        for (int j = 0; j < 4; ++j)
            if (n0 + (tx << 2) + j < N) Cr[j] = acc[i][j];
    }
}

// 4-wave scan per (b,h), lgkm-only barriers (3/step), prefetch never drained.
// Wave w: q/n-window [16w,16w+16). Lane l: state row l (16 cols/wave),
// conv channel w*64+l (waves 0-2), R rows l over window (registers).
__global__ __launch_bounds__(256, 1) void mamba_scan3(
    const float* __restrict__ zx,      // [4096, DIP]
    const float* __restrict__ conv_w,  // [4608, 4]
    const float* __restrict__ conv_b,  // [4608]
    const float* __restrict__ R_x,     // [24,64,64]
    const float* __restrict__ R_B,
    const float* __restrict__ R_C,
    const float* __restrict__ R_dt,    // [24,64]
    const float* __restrict__ dt_bias, // [24]
    const float* __restrict__ A_log,   // [24]
    const float* __restrict__ Dvec,    // [24,64]
    float* __restrict__ yz)            // [4096, 1536]
{
    const int b = blockIdx.x / NHEADS;
    const int h = blockIdx.x % NHEADS;
    const int tid = threadIdx.x;
    const int w = tid >> 6;
    const int l = tid & 63;

    __shared__ __attribute__((aligned(16))) float px[4][64];
    __shared__ __attribute__((aligned(16))) float pB[4][64];
    __shared__ __attribute__((aligned(16))) float pC[4][64];
    __shared__ __attribute__((aligned(16))) float py[4][64];
    __shared__ __attribute__((aligned(16))) float xl[64];
    __shared__ __attribute__((aligned(16))) float Bml[64];
    __shared__ __attribute__((aligned(16))) float Cml[64];
    __shared__ float pdt[4];
    __shared__ float sc[2];

    // R fragments: rows l, columns [16w, 16w+16)
    float Rx[16], Rb[16], Rc[16], Rdw[16], Dw[16];
    {
        const size_t rowoff = ((size_t)h * 64 + l) * 64 + w * 16;
#pragma unroll
        for (int j = 0; j < 16; j += 4) {
            const float4 v = *(const float4*)(R_x + rowoff + j);
            Rx[j] = v.x; Rx[j+1] = v.y; Rx[j+2] = v.z; Rx[j+3] = v.w;
        }
#pragma unroll
        for (int j = 0; j < 16; j += 4) {
            const float4 v = *(const float4*)(R_B + rowoff + j);
            Rb[j] = v.x; Rb[j+1] = v.y; Rb[j+2] = v.z; Rb[j+3] = v.w;
        }
#pragma unroll
        for (int j = 0; j < 16; j += 4) {
            const float4 v = *(const float4*)(R_C + rowoff + j);
            Rc[j] = v.x; Rc[j+1] = v.y; Rc[j+2] = v.z; Rc[j+3] = v.w;
        }
#pragma unroll
        for (int j = 0; j < 16; j += 4) {
            const float4 v = *(const float4*)(R_dt + h * 64 + w * 16 + j);
            Rdw[j] = v.x; Rdw[j+1] = v.y; Rdw[j+2] = v.z; Rdw[j+3] = v.w;
        }
#pragma unroll
        for (int j = 0; j < 16; j += 4) {
            const float4 v = *(const float4*)(Dvec + h * 64 + w * 16 + j);
            Dw[j] = v.x; Dw[j+1] = v.y; Dw[j+2] = v.z; Dw[j+3] = v.w;
        }
    }
    const float Aval = -__expf(A_log[h]);
    const float bias = dt_bias[h];
    const float dval = Dvec[h * 64 + l];

    // conv: waves 0..2 own channel ch = w*64+l
    float cw0 = 0.f, cw1 = 0.f, cw2 = 0.f, cw3 = 0.f, cb = 0.f;
    float hh0 = 0.f, hh1 = 0.f, hh2 = 0.f;
    const int ch = w * 64 + l;
    if (w < 3) {
        const float* cwp = conv_w + ((size_t)h * CDPH + ch) * 4;
        cw0 = cwp[0]; cw1 = cwp[1]; cw2 = cwp[2]; cw3 = cwp[3];
        cb = conv_b[h * CDPH + ch];
    }

    const float* xbc = zx + (size_t)b * LSEQ * DIP + DINNER + h * CDPH;
    const float* zb  = zx + (size_t)b * LSEQ * DIP + h * HD;
    const float* dtr = zx + (size_t)b * LSEQ * DIP + DINNER + CONVDIM + h;
    float* yzb = yz + (size_t)b * LSEQ * DINNER + h * HD;

    float st[16];
#pragma unroll
    for (int j = 0; j < 16; ++j) st[j] = 0.f;

    py[w][l] = 0.f;
    if (w == 0) xl[l] = 0.f;
    __syncthreads();  // once, pre-loop

    float v_cur = 0.f, z_cur = 0.f, dtr_cur = 0.f;
    if (w < 3) v_cur = xbc[ch];
    else { z_cur = zb[l]; if (l == 0) dtr_cur = dtr[0]; }

    for (int t = 0; t < LSEQ; ++t) {
        // ---- conv (register-only) ----
        float xc = 0.f;
        if (w < 3) {
            xc = fmaf(cw3, v_cur, fmaf(cw2, hh2, fmaf(cw1, hh1, fmaf(cw0, hh0, cb))));
            hh0 = hh1; hh1 = hh2; hh2 = v_cur;
        }

        // ---- prefetch t+1: stays in flight across ALL barriers ----
        const size_t roff = (size_t)((t + 1 < LSEQ) ? t + 1 : t) * DIP;
        float v_nxt = 0.f, z_nxt = 0.f, dtr_nxt = 0.f;
        if (w < 3) v_nxt = xbc[roff + ch];
        else { z_nxt = zb[roff + l]; if (l == 0) dtr_nxt = dtr[roff]; }

        // ---- phase A: form y_prev window from partials, then 4 dots ----
        float yq[16];
#pragma unroll
        for (int c = 0; c < 4; ++c) {
            const int o = w * 16 + c * 4;
            const float4 p0 = *(const float4*)&py[0][o];
            const float4 p1 = *(const float4*)&py[1][o];
            const float4 p2 = *(const float4*)&py[2][o];
            const float4 p3 = *(const float4*)&py[3][o];
            const float4 xv = *(const float4*)&xl[o];
            yq[c*4+0] = ((p0.x + p1.x) + (p2.x + p3.x)) + Dw[c*4+0] * xv.x;
            yq[c*4+1] = ((p0.y + p1.y) + (p2.y + p3.y)) + Dw[c*4+1] * xv.y;
            yq[c*4+2] = ((p0.z + p1.z) + (p2.z + p3.z)) + Dw[c*4+2] * xv.z;
            yq[c*4+3] = ((p0.w + p1.w) + (p2.w + p3.w)) + Dw[c*4+3] * xv.w;
        }
        float ax0 = 0.f, ax1 = 0.f, ab0 = 0.f, ab1 = 0.f;
        float ac0 = 0.f, ac1 = 0.f, ad0 = 0.f, ad1 = 0.f;
#pragma unroll
        for (int j = 0; j < 16; j += 2) {
            ax0 = fmaf(Rx[j],   yq[j],   ax0);
            ax1 = fmaf(Rx[j+1], yq[j+1], ax1);
            ab0 = fmaf(Rb[j],   yq[j],   ab0);
            ab1 = fmaf(Rb[j+1], yq[j+1], ab1);
            ac0 = fmaf(Rc[j],   yq[j],   ac0);
            ac1 = fmaf(Rc[j+1], yq[j+1], ac1);
            ad0 = fmaf(Rdw[j],   yq[j],   ad0);
            ad1 = fmaf(Rdw[j+1], yq[j+1], ad1);
        }
        px[w][l] = ax0 + ax1;
        pB[w][l] = ab0 + ab1;
        pC[w][l] = ac0 + ac1;
        if (l == 0) pdt[w] = ad0 + ad1;
        WBAR();  // 1

        // ---- reduce + silu (each family by its conv-owning wave) ----
        if (w == 0) {
            xl[l] = siluf(xc + ((px[0][l] + px[1][l]) + (px[2][l] + px[3][l])));
        } else if (w == 1) {
            Bml[l] = siluf(xc + ((pB[0][l] + pB[1][l]) + (pB[2][l] + pB[3][l])));
        } else if (w == 2) {
            Cml[l] = siluf(xc + ((pC[0][l] + pC[1][l]) + (pC[2][l] + pC[3][l])));
        } else if (l == 0) {
            const float dv = dtr_cur + ((pdt[0] + pdt[1]) + (pdt[2] + pdt[3])) + bias;
            const float dtv = (dv > 20.f) ? dv : log1pf(__expf(dv));
            sc[0] = dtv;
            sc[1] = __expf(dtv * Aval);
        }
        WBAR();  // 2

        // ---- phase B: state update + partial output dot ----
        const float dtv = sc[0], dAv = sc[1];
        const float xme = xl[l];
        const float kx = dtv * xme;
        float yp0 = 0.f, yp1 = 0.f;
#pragma unroll
        for (int c = 0; c < 4; ++c) {
            const int o = w * 16 + c * 4;
            const float4 bm = *(const float4*)&Bml[o];
            const float4 cm = *(const float4*)&Cml[o];
            st[c*4+0] = fmaf(st[c*4+0], dAv, kx * bm.x);
            yp0 = fmaf(st[c*4+0], cm.x, yp0);
            st[c*4+1] = fmaf(st[c*4+1], dAv, kx * bm.y);
            yp1 = fmaf(st[c*4+1], cm.y, yp1);
            st[c*4+2] = fmaf(st[c*4+2], dAv, kx * bm.z);
            yp0 = fmaf(st[c*4+2], cm.z, yp0);
            st[c*4+3] = fmaf(st[c*4+3], dAv, kx * bm.w);
            yp1 = fmaf(st[c*4+3], cm.w, yp1);
        }
        py[w][l] = yp0 + yp1;
        WBAR();  // 3

        // ---- wave3: gated output store (overlaps next step's phase A) ----
        if (w == 3) {
            const float yfull = ((py[0][l] + py[1][l]) + (py[2][l] + py[3][l]))
                              + dval * xme;
            yzb[(size_t)t * DINNER + l] = yfull * siluf(z_cur);
        }

        v_cur = v_nxt; z_cur = z_nxt; dtr_cur = dtr_nxt;
    }
}

extern "C" void kernel_launch(void* const* d_in, const int* in_sizes, int n_in,
                              void* d_out, int out_size, void* d_ws, size_t ws_size,
                              hipStream_t stream) {
    const float* u       = (const float*)d_in[0];
    const float* W_in    = (const float*)d_in[1];
    const float* conv_w  = (const float*)d_in[2];
    const float* conv_b  = (const float*)d_in[3];
    const float* R_x     = (const float*)d_in[4];
    const float* R_B     = (const float*)d_in[5];
    const float* R_C     = (const float*)d_in[6];
    const float* R_dt    = (const float*)d_in[7];
    const float* dt_bias = (const float*)d_in[8];
    const float* A_log   = (const float*)d_in[9];
    const float* Dv      = (const float*)d_in[10];
    const float* W_out   = (const float*)d_in[11];
    float* out = (float*)d_out;

    float* zx = (float*)d_ws;                      // [4096, 6168]
    float* yz = zx + (size_t)MROWS * DIP;          // [4096, 1536]

    {   // in-projection
        const int M = MROWS, N = DIP, K = DMODEL;
        const int grid = (M / 128) * ((N + 63) / 64);
        gemm_nt_f32<<<grid, 256, 0, stream>>>(u, W_in, zx, M, N, K);
    }
    mamba_scan3<<<B_SZ * NHEADS, 256, 0, stream>>>(
        zx, conv_w, conv_b, R_x, R_B, R_C, R_dt, dt_bias, A_log, Dv, yz);
    {   // out-projection
        const int M = MROWS, N = DMODEL, K = DINNER;
        const int grid = (M / 128) * ((N + 63) / 64);
        gemm_nt_f32<<<grid, 256, 0, stream>>>(yz, W_out, out, M, N, K);
    }
}